// Round 15
// baseline (223.748 us; speedup 1.0000x reference)
//
#include <hip/hip_runtime.h>

#define N_NODES 4096
#define F_IN 512
#define NHID 256
#define HD 1024        // 4 heads * 256
#define NPAD 1152      // padded N for adjacency GEMM (9 * 128)

typedef _Float16 half8 __attribute__((ext_vector_type(8)));
typedef _Float16 half4 __attribute__((ext_vector_type(4)));
typedef float floatx4 __attribute__((ext_vector_type(4)));
typedef float float4v __attribute__((ext_vector_type(4)));
typedef int int4v __attribute__((ext_vector_type(4)));
typedef unsigned int uint4v __attribute__((ext_vector_type(4)));

__device__ __forceinline__ float bf2f(unsigned short u) {
  union { unsigned int i; float f; } x; x.i = ((unsigned int)u) << 16; return x.f;
}

__device__ __forceinline__ void async_copy16(const void* g, void* l) {
  __builtin_amdgcn_global_load_lds((const __attribute__((address_space(1))) void*)g,
                                   (__attribute__((address_space(3))) void*)l, 16, 0, 0);
}

// ---------------- GEMM core (f16 A): C[M x ldc] = A[M x K] * BT[N x K]^T, fp32 accum ----------------
// 128x128 tile, BK=32, 256 threads (4 waves, each 64x64 via 4x4 mfma_f32_16x16x32_f16).
// T3+T4 counted-vmcnt triple-buffer pipeline (proven r4/r9/r11/r14 structure; best total 186.2us).
// LEDGER r3/r6: LDS bank conflicts off the critical path at 64B rows (0-conflict endpoint = no gain).
// LEDGER r4/r5: not L2-BW-bound; 4 schedule variants all ~60+/-3us at the adj shape.
// LEDGER r7/r8: per-lane A-fragment global loads FAIL (64 lines/wave); A must stage coalesced.
// LEDGER r10: int32->f16 cvt at ds_WRITE time FAILS (rides lgkm path BEFORE the wait).
// LEDGER r12: device-scope atomics to one cache line from 4096 blocks = ~180us ping-pong.
// LEDGER r14->r15: cvt moved to FRAGMENT-READ time in gemm_adj (after lgkmcnt, VALU slack),
//   with rule-#21 both-sides swizzle (int32 rows = 128B stride = the G4 32-way trap).
template <typename OutT>
__device__ __forceinline__ void gemm_core(
    const _Float16* __restrict__ A, const _Float16* __restrict__ BT,
    OutT* __restrict__ C, int K, int ldc, int klen, long csz,
    int lin, int nbx, int nby, int total,
    _Float16* __restrict__ sA, _Float16* __restrict__ sB)
{
  // ---- XCD-aware swizzle: same-XCD blocks get contiguous (kz, m, n-fastest) tiles ----
  int tile = ((total & 7) == 0) ? ((lin & 7) * (total >> 3) + (lin >> 3)) : lin;
  const int n_idx = tile % nbx;
  const int rem   = tile / nbx;
  const int m_idx = rem % nby;
  const int kz    = rem / nby;

  const int n0 = n_idx * 128;
  const int m0 = m_idx * 128;
  const int kbeg = kz * klen;
  OutT* Cz = C + (long)kz * csz;

  const int t = threadIdx.x;
  const int w = t >> 6;
  const int lane = t & 63;
  const int wm = (w >> 1) << 6;
  const int wn = (w & 1) << 6;

  floatx4 acc[4][4] = {};

  const int l4 = lane >> 2;         // 0..15 (row within 16-row chunk)
  const int kk = (lane & 3) << 3;   // k element offset 0,8,16,24
  const int c0 = w << 1;            // this wave stages chunks c0, c0+1

  const _Float16* gA = A + (long)m0 * K;
  const _Float16* gBT = BT + (long)n0 * K;

  const int koff = (lane >> 4) << 3;   // quad*8
  const int rA = wm + (lane & 15);
  const int rB = wn + (lane & 15);

  const int nt = klen >> 5;            // number of BK=32 K-steps

  auto STAGE = [&](int buf, int k0) {
#pragma unroll
    for (int p = 0; p < 2; ++p) {
      const int c = c0 + p;
      const int row = c * 16 + l4;
      async_copy16(gA + (long)row * K + k0 + kk, &sA[buf * 4096 + c * 512 + lane * 8]);
      async_copy16(gBT + (long)row * K + k0 + kk, &sB[buf * 4096 + c * 512 + lane * 8]);
    }
  };

  // prologue: stage tiles 0 and 1 (8 loads/thread in flight)
  STAGE(0, kbeg);
  if (nt > 1) STAGE(1, kbeg + 32);

  int cur = 0;
  for (int it = 0; it < nt; ++it) {
    const int k0 = kbeg + it * 32;

    // wait for tile `it` (4 loads) to land; tile it+1's 4 stay in flight
    if (it + 1 < nt) asm volatile("s_waitcnt vmcnt(4)" ::: "memory");
    else             asm volatile("s_waitcnt vmcnt(0)" ::: "memory");
    __builtin_amdgcn_s_barrier();     // all waves' tile-`it` loads visible

    half8 af[4], bf[4];
#pragma unroll
    for (int i = 0; i < 4; ++i)
      af[i] = *(const half8*)&sA[cur * 4096 + (rA + i * 16) * 32 + koff];
#pragma unroll
    for (int i = 0; i < 4; ++i)
      bf[i] = *(const half8*)&sB[cur * 4096 + (rB + i * 16) * 32 + koff];

    asm volatile("s_waitcnt lgkmcnt(0)" ::: "memory");
    __builtin_amdgcn_sched_barrier(0);   // rule #18: MFMA must not hoist past the wait

    // stage tile it+2 into the buffer freed above (held tile it-1; all reads done)
    const int nxt = (cur + 2 >= 3) ? cur - 1 : cur + 2;
    if (it + 2 < nt) STAGE(nxt, k0 + 64);

#pragma unroll
    for (int i = 0; i < 4; ++i)
#pragma unroll
      for (int j = 0; j < 4; ++j)
        acc[i][j] = __builtin_amdgcn_mfma_f32_16x16x32_f16(af[i], bf[j], acc[i][j], 0, 0, 0);

    cur = (cur + 1 >= 3) ? 0 : cur + 1;
  }

  const int q4 = (lane >> 4) << 2;
#pragma unroll
  for (int i = 0; i < 4; ++i) {
#pragma unroll
    for (int j = 0; j < 4; ++j) {
      const int gr = m0 + wm + i * 16 + q4;
      const int gc = n0 + wn + j * 16 + (lane & 15);
#pragma unroll
      for (int r = 0; r < 4; ++r)
        Cz[(long)(gr + r) * ldc + gc] = (OutT)acc[i][j][r];
    }
  }
}

template <typename OutT>
__global__ __launch_bounds__(256) void gemm_bt(
    const _Float16* __restrict__ A, const _Float16* __restrict__ BT,
    OutT* __restrict__ C, int K, int ldc, int klen, long csz)
{
  __shared__ _Float16 sA[3 * 128 * 32];
  __shared__ _Float16 sB[3 * 128 * 32];
  const int nbx = gridDim.x, nby = gridDim.y;
  const int total = nbx * nby * gridDim.z;
  const int lin = blockIdx.x + nbx * (blockIdx.y + nby * blockIdx.z);
  gemm_core<OutT>(A, BT, C, K, ldc, klen, csz, lin, nbx, nby, total, sA, sB);
}

// ---------------- adj GEMM, int32 A staged raw + converted at fragment-read ----------------
// S_z = adj(int32) @ VT^T. Kills the 96MB standalone cvt pass + the 32MB adjF buffer.
// A staged as raw int32 via global_load_lds (coalesced: 8 lanes x 16B = one 128B row).
// int32 rows are 128B stride -> G4 32-way conflict if linear; rule-#21 both-sides swizzle:
//   LDS[r][slot c] holds global 16B-slot c^(r&7) (achieved by pre-swizzling the SOURCE
//   slot per staging lane: src = (t&7)^((t>>3)&7), LDS dest stays linear);
//   read uses slot (2g)^(r&7), (2g+1)^(r&7) -> bank census 8/bank = same as benign f16 path.
// Convert AFTER lgkmcnt(0) (not at ds_write, r10's failure): 0/1 clamp + (lo+hi<<16)*0x3C00
// pack, ~32 VALU/step against 14% VALUBusy slack. vmcnt(6) boundary (6 loads/tile).
__global__ __launch_bounds__(256) void gemm_adj_kernel(
    const int* __restrict__ adj, const _Float16* __restrict__ BT, float* __restrict__ C,
    int K, int ldc, int klen, long csz)
{
  __shared__ int      sAi[3 * 128 * 32];  // 48 KB raw int32 A
  __shared__ _Float16 sB [3 * 128 * 32];  // 24 KB f16 B
  const int nbx = gridDim.x, nby = gridDim.y;
  const int total = nbx * nby * gridDim.z;
  const int lin = blockIdx.x + nbx * (blockIdx.y + nby * blockIdx.z);

  int tile = ((total & 7) == 0) ? ((lin & 7) * (total >> 3) + (lin >> 3)) : lin;
  const int n_idx = tile % nbx;
  const int rem   = tile / nbx;
  const int m_idx = rem % nby;
  const int kz    = rem / nby;

  const int n0 = n_idx * 128;
  const int m0 = m_idx * 128;
  const int kbeg = kz * klen;
  float* Cz = C + (long)kz * csz;

  const int t = threadIdx.x;
  const int w = t >> 6;
  const int lane = t & 63;
  const int wm = (w >> 1) << 6;
  const int wn = (w & 1) << 6;

  floatx4 acc[4][4] = {};

  // B staging (unchanged gload_lds path, 64B f16 rows = benign banks)
  const int l4 = lane >> 2;
  const int kkB = (lane & 3) << 3;
  const int c0 = w << 1;
  const _Float16* gBT = BT + (long)n0 * K;

  // A staging: 4 rounds x 256 chunks; chunk q*256+t -> row q*32+(t>>3), LDS slot t&7;
  // source slot pre-swizzled so LDS[r][c] = global slot c^(r&7).
  const int* gAi = adj + (long)m0 * K;
  const int arow  = t >> 3;                    // row within each 32-row round
  const int aslot = (t & 7) ^ ((t >> 3) & 7);  // pre-swizzled global 16B-slot

  const int koff = (lane >> 4) << 3;           // k-offset (elements)
  const int g2 = (lane >> 4) << 1;             // even slot index 2g
  const int rA = wm + (lane & 15);
  const int rB = wn + (lane & 15);

  const int nt = klen >> 5;

  auto STAGE = [&](int buf, int k0) {
#pragma unroll
    for (int q = 0; q < 4; ++q) {
      const int row = q * 32 + arow;
      async_copy16(gAi + (long)row * K + k0 + aslot * 4,
                   &sAi[buf * 4096 + (q * 256 + t) * 4]);
    }
#pragma unroll
    for (int p = 0; p < 2; ++p) {
      const int c = c0 + p;
      const int row = c * 16 + l4;
      async_copy16(gBT + (long)row * K + k0 + kkB, &sB[buf * 4096 + c * 512 + lane * 8]);
    }
  };

  STAGE(0, kbeg);
  if (nt > 1) STAGE(1, kbeg + 32);

  int cur = 0;
  for (int it = 0; it < nt; ++it) {
    const int k0 = kbeg + it * 32;
    // 6 loads/tile: boundary retires tile `it`, leaves tile it+1's 6 in flight
    if (it + 1 < nt) asm volatile("s_waitcnt vmcnt(6)" ::: "memory");
    else             asm volatile("s_waitcnt vmcnt(0)" ::: "memory");
    __builtin_amdgcn_s_barrier();

    int4v a0[4], a1[4];
    half8 bf[4];
#pragma unroll
    for (int i = 0; i < 4; ++i) {
      const int r = rA + i * 16;
      const int rm = r & 7;
      a0[i] = *(const int4v*)&sAi[cur * 4096 + r * 32 + ((g2) ^ rm) * 4];
      a1[i] = *(const int4v*)&sAi[cur * 4096 + r * 32 + ((g2 + 1) ^ rm) * 4];
    }
#pragma unroll
    for (int j = 0; j < 4; ++j)
      bf[j] = *(const half8*)&sB[cur * 4096 + (rB + j * 16) * 32 + koff];

    asm volatile("s_waitcnt lgkmcnt(0)" ::: "memory");
    __builtin_amdgcn_sched_barrier(0);   // rule #18: pack/MFMA must not hoist past the wait

    const int nxt = (cur + 2 >= 3) ? cur - 1 : cur + 2;
    if (it + 2 < nt) STAGE(nxt, k0 + 64);

    // convert raw 0/1 int32 -> f16 fragments (r10-validated pack, now post-wait)
    half8 af[4];
#pragma unroll
    for (int i = 0; i < 4; ++i) {
      union { unsigned u[4]; half8 h; } pk;
      unsigned x0 = (unsigned)a0[i][0], x1 = (unsigned)a0[i][1],
               x2 = (unsigned)a0[i][2], x3 = (unsigned)a0[i][3],
               y0 = (unsigned)a1[i][0], y1 = (unsigned)a1[i][1],
               y2 = (unsigned)a1[i][2], y3 = (unsigned)a1[i][3];
      x0 = x0 < 1u ? x0 : 1u; x1 = x1 < 1u ? x1 : 1u;
      x2 = x2 < 1u ? x2 : 1u; x3 = x3 < 1u ? x3 : 1u;
      y0 = y0 < 1u ? y0 : 1u; y1 = y1 < 1u ? y1 : 1u;
      y2 = y2 < 1u ? y2 : 1u; y3 = y3 < 1u ? y3 : 1u;
      pk.u[0] = (x0 + (x1 << 16)) * 0x3C00u;
      pk.u[1] = (x2 + (x3 << 16)) * 0x3C00u;
      pk.u[2] = (y0 + (y1 << 16)) * 0x3C00u;
      pk.u[3] = (y2 + (y3 << 16)) * 0x3C00u;
      af[i] = pk.h;
    }

#pragma unroll
    for (int i = 0; i < 4; ++i)
#pragma unroll
      for (int j = 0; j < 4; ++j)
        acc[i][j] = __builtin_amdgcn_mfma_f32_16x16x32_f16(af[i], bf[j], acc[i][j], 0, 0, 0);

    cur = (cur + 1 >= 3) ? 0 : cur + 1;
  }

  const int q4 = (lane >> 4) << 2;
#pragma unroll
  for (int i = 0; i < 4; ++i) {
#pragma unroll
    for (int j = 0; j < 4; ++j) {
      const int gr = m0 + wm + i * 16 + q4;
      const int gc = n0 + wn + j * 16 + (lane & 15);
#pragma unroll
      for (int r = 0; r < 4; ++r)
        Cz[(long)(gr + r) * ldc + gc] = acc[i][j][r];
    }
  }
}

// ---------------- prep: detect + cvt_h + cvt_a + transpose_w (1 launch) ----------------
// LEDGER r10->r11: per-block local flag recompute (2KB L2-broadcast) kills the flag round-trip.
// r15: adj cvt eliminated entirely (moved into gemm_adj at fragment-read time).
// Blocks 0..1023: cvt_h; 1024: cvt_a; 1025..1152: transpose_w (8x16).
__global__ __launch_bounds__(256) void prep_kernel(
    const void* __restrict__ h, _Float16* __restrict__ hF,
    const void* __restrict__ a, float* __restrict__ aF,
    const void* __restrict__ W, _Float16* __restrict__ WT)
{
  const int t = threadIdx.x;
  __shared__ int red[256];
  __shared__ _Float16 tile[64][72];
  const unsigned short* hb = (const unsigned short*)h;
  int cnt = 0;
#pragma unroll
  for (int q = 0; q < 4; ++q) {
    int e = (hb[t * 4 + q] >> 7) & 0xFF;
    cnt += (e >= 115 && e <= 135) ? 1 : 0;
  }
  red[t] = cnt; __syncthreads();
  for (int s = 128; s > 0; s >>= 1) { if (t < s) red[t] += red[t + s]; __syncthreads(); }
  const int bf = (red[0] >= 900) ? 1 : 0;   // uniform across block after reduce
  __syncthreads();

  const int b = blockIdx.x;
  if (b < 1024) {
    // ---- cvt_h: h (bf16 or fp32) -> f16, 8 elems/thread ----
    const int i = b * 256 + t;
    half8 o;
    if (bf) {
      union { uint4v v; unsigned short s[8]; } u;
      u.v = ((const uint4v*)h)[i];
#pragma unroll
      for (int e = 0; e < 8; ++e) o[e] = (_Float16)bf2f(u.s[e]);
    } else {
      const float4v* f = (const float4v*)h + 2 * i;
      float4v x0 = f[0], x1 = f[1];
#pragma unroll
      for (int e = 0; e < 4; ++e) { o[e] = (_Float16)x0[e]; o[4 + e] = (_Float16)x1[e]; }
    }
    ((half8*)hF)[i] = o;
  } else if (b == 1024) {
    // ---- cvt_a: a (bf16 or fp32) -> fp32, 2048 elems ----
#pragma unroll
    for (int e = 0; e < 8; ++e) {
      int idx = t * 8 + e;
      aF[idx] = bf ? bf2f(((const unsigned short*)a)[idx]) : ((const float*)a)[idx];
    }
  } else {
    // ---- transpose_w: W[512 x 1024] -> WT[1024 x 512] f16 ----
    const int bb = b - 1025;
    const int k0 = (bb & 7) * 64, n0 = (bb >> 3) * 64;
    const int r = t >> 3, c = t & 7;
#pragma unroll
    for (int q = 0; q < 2; ++q) {
      int k = r + q * 32;
      half8 v;
      if (bf) {
        union { uint4v vv; unsigned short s[8]; } u;
        u.vv = *(const uint4v*)&((const unsigned short*)W)[(long)(k0 + k) * HD + n0 + c * 8];
#pragma unroll
        for (int e = 0; e < 8; ++e) v[e] = (_Float16)bf2f(u.s[e]);
      } else {
        const float4v* f = (const float4v*)&((const float*)W)[(long)(k0 + k) * HD + n0 + c * 8];
        float4v x0 = f[0], x1 = f[1];
#pragma unroll
        for (int e = 0; e < 4; ++e) { v[e] = (_Float16)x0[e]; v[4 + e] = (_Float16)x1[e]; }
      }
      *(half8*)&tile[k][c * 8] = v;
    }
    __syncthreads();
#pragma unroll
    for (int q = 0; q < 2; ++q) {
      int n = r + q * 32;
      half8 o;
#pragma unroll
      for (int e = 0; e < 8; ++e) o[e] = tile[c * 8 + e][n];
      *(half8*)&WT[(long)(n0 + n) * F_IN + k0 + c * 8] = o;
    }
  }
}

// ---------------- tgt[h,i] = sum_d leaky_relu(ht[i, h*256+d]) * aF[h, 256+d]  (no atomics) ----------------
__global__ void tgt_kernel(const _Float16* __restrict__ ht, const float* __restrict__ aF,
                           float* __restrict__ tgt) {
  const int i = blockIdx.x;
  const int t = threadIdx.x, h = t >> 6, lane = t & 63;
  half4 v = *(const half4*)&ht[(long)i * HD + h * NHID + lane * 4];
  float4v av = *(const float4v*)&aF[h * 512 + NHID + lane * 4];
  float s = 0.f;
#pragma unroll
  for (int e = 0; e < 4; ++e) {
    float x = (float)v[e];
    x = x > 0.f ? x : 0.1f * x;
    s += x * av[e];
  }
#pragma unroll
  for (int o = 32; o > 0; o >>= 1) s += __shfl_down(s, o);
  if (lane == 0) tgt[h * N_NODES + i] = s;
}

// ---------------- scaled transpose + in-block row-max + inline w=exp(tgt-m) ----------------
// LEDGER r12->r13: maxexp eliminated WITHOUT atomics: per-block local row-max recompute
// (L2-broadcast + wave/LDS reduce; max order-independent -> bit-identical m).
// grid (64,17): y<16 = transpose tiles; y==16 = VT w-rows 1024..1027.
__global__ void scaled_transpose_kernel(const _Float16* __restrict__ ht, const float* __restrict__ tgt,
                                        _Float16* __restrict__ VT) {
  __shared__ _Float16 tile[64][72];
  __shared__ float red[4];
  const int j0 = blockIdx.x * 64;
  const int t = threadIdx.x;
  const int w = t >> 6, lane = t & 63;

  if (blockIdx.y == 16) {
    // wave w: reduce head w's row (64 lanes x 64 elems), then write 64 w-values
    const float* row = tgt + w * N_NODES;
    float m = -3.0e38f;
#pragma unroll
    for (int q = 0; q < 16; ++q) {
      float4v v = *(const float4v*)&row[(lane + q * 64) * 4];
#pragma unroll
      for (int e = 0; e < 4; ++e) m = fmaxf(m, v[e]);
    }
#pragma unroll
    for (int o = 32; o > 0; o >>= 1) m = fmaxf(m, __shfl_down(m, o));
    if (lane == 0) red[w] = m;
    __syncthreads();
    const float mh = red[w];
    const int j = j0 + lane;
    VT[(long)(HD + w) * N_NODES + j] = (_Float16)__expf(row[j] - mh);
    return;
  }

  const int n0 = blockIdx.y * 64;
  const int h = n0 >> 8;
  const float* row = tgt + h * N_NODES;
  const int r = t >> 3, c = t & 7;
  // tile loads + row-max partials both land before the single barrier
#pragma unroll
  for (int q = 0; q < 2; ++q) {
    int j = r + q * 32;
    *(half8*)&tile[j][c * 8] = *(const half8*)&ht[(long)(j0 + j) * HD + n0 + c * 8];
  }
  float m = -3.0e38f;
#pragma unroll
  for (int q = 0; q < 4; ++q) {
    float4v v = *(const float4v*)&row[(t + q * 256) * 4];
#pragma unroll
    for (int e = 0; e < 4; ++e) m = fmaxf(m, v[e]);
  }
#pragma unroll
  for (int o = 32; o > 0; o >>= 1) m = fmaxf(m, __shfl_down(m, o));
  if (lane == 0) red[w] = m;
  __syncthreads();
  m = fmaxf(fmaxf(red[0], red[1]), fmaxf(red[2], red[3]));

  float w8[8];
#pragma unroll
  for (int e = 0; e < 8; ++e)
    w8[e] = __expf(row[j0 + c * 8 + e] - m);
#pragma unroll
  for (int q = 0; q < 2; ++q) {
    int n = r + q * 32;
    half8 o;
#pragma unroll
    for (int e = 0; e < 8; ++e) {
      int j = c * 8 + e;
      o[e] = (_Float16)(w8[e] * (float)tile[j][n]);
    }
    *(half8*)&VT[(long)(n0 + n) * N_NODES + j0 + c * 8] = o;
  }
}

// ---------------- out[i,d] = fp32( 0.25 * sum_h (sum_z Sz[i, h*256+d]) / (sum_z Sz[i, 1024+h]) ) ----------------
__global__ void epilogue_kernel(const float* __restrict__ S, float* __restrict__ out, int ns) {
  const int i = blockIdx.x, d = threadIdx.x;
  const long SZ = (long)N_NODES * NPAD;
  float num[4] = {0.f, 0.f, 0.f, 0.f};
  float den[4] = {0.f, 0.f, 0.f, 0.f};
  for (int z = 0; z < ns; ++z) {
    const float* row = S + z * SZ + (long)i * NPAD;
#pragma unroll
    for (int h = 0; h < 4; ++h) {
      num[h] += row[h * NHID + d];
      den[h] += row[HD + h];
    }
  }
  float r = 0.f;
#pragma unroll
  for (int h = 0; h < 4; ++h) r += num[h] / den[h];
  out[(long)i * NHID + d] = 0.25f * r;
}

extern "C" void kernel_launch(void* const* d_in, const int* in_sizes, int n_in,
                              void* d_out, int out_size, void* d_ws, size_t ws_size,
                              hipStream_t stream) {
  // map inputs by element count: h=2097152, adj=16777216, W=524288, a=2048
  const void* h = nullptr; const int* adj = nullptr; const void* W = nullptr; const void* a = nullptr;
  for (int i = 0; i < n_in; ++i) {
    switch (in_sizes[i]) {
      case 2097152:  h   = d_in[i]; break;
      case 16777216: adj = (const int*)d_in[i]; break;
      case 524288:   W   = d_in[i]; break;
      case 2048:     a   = d_in[i]; break;
      default: break;
    }
  }
  float* out = (float*)d_out;  // fp32 [4096,256]

  char* ws = (char*)d_ws;
  const size_t OFF_VT   = 0;                       //  9,437,184  VT [1152 x 4096] f16
  const size_t OFF_TGT  = OFF_VT + 9437184;        //     65,536  tgt fp32 [4 x 4096]
  const size_t OFF_WBUF = OFF_TGT + 65536;         //     65,536  (spare)
  const size_t OFF_M    = OFF_WBUF + 65536;        //        256  (spare)
  const size_t OFF_AF   = OFF_M + 256;             //      8,192  a as fp32
  const size_t OFF_X    = OFF_AF + 8192;           // overlap region
  const size_t SPART    = 18874368;                // one fp32 S partial [4096 x 1152]

  // split-K ns=2 (LEDGER r9: halves S write + epilogue re-read vs ns=4; 576 blocks saturate)
  int ns = 1;
  if      (ws_size >= OFF_X + 2 * SPART) ns = 2;
  if (ws_size < OFF_X + SPART || !h || !adj || !W || !a) return;

  _Float16* VT   = (_Float16*)(ws + OFF_VT);
  float*    tgt  = (float*)(ws + OFF_TGT);
  float*    aF   = (float*)(ws + OFF_AF);
  // region X: hF/WT/ht live until scaled_transpose; S partials (adj-GEMM output) alias them after
  _Float16* hF = (_Float16*)(ws + OFF_X);                  // 4,194,304
  _Float16* WT = (_Float16*)(ws + OFF_X + 4194304);        // 1,048,576
  _Float16* ht = (_Float16*)(ws + OFF_X + 5242880);        // 8,388,608
  float*    S  = (float*)(ws + OFF_X);                     // ns x 18,874,368 (aliases dead hF/WT/ht)

  // prep: detect(local) + cvt_h + cvt_a + transpose_w in ONE launch
  prep_kernel<<<1153, 256, 0, stream>>>(h, hF, a, aF, W, WT);
  // ht[4096 x 1024] = h @ W  (standalone: uncontended HBM/L2)
  gemm_bt<_Float16><<<dim3(8, 32, 1), 256, 0, stream>>>(hF, WT, ht, F_IN, HD, F_IN, 0);
  tgt_kernel<<<4096, 256, 0, stream>>>(ht, aF, tgt);
  scaled_transpose_kernel<<<dim3(64, 17), 256, 0, stream>>>(ht, tgt, VT);
  // S_z[4096 x 1152] = adj(int32, converted at fragment-read) @ [w*ht | w] over K-slice z
  gemm_adj_kernel<<<dim3(9, 32, ns), 256, 0, stream>>>(adj, VT, S, N_NODES, NPAD,
                                                       N_NODES / ns, (long)N_NODES * NPAD);
  epilogue_kernel<<<4096, 256, 0, stream>>>(S, out, ns);
}

// Round 16
// 185.202 us; speedup vs baseline: 1.2081x; 1.2081x over previous
//
#include <hip/hip_runtime.h>

#define N_NODES 4096
#define F_IN 512
#define NHID 256
#define HD 1024        // 4 heads * 256
#define NPAD 1152      // padded N for adjacency GEMM (9 * 128)

typedef _Float16 half8 __attribute__((ext_vector_type(8)));
typedef _Float16 half4 __attribute__((ext_vector_type(4)));
typedef float floatx4 __attribute__((ext_vector_type(4)));
typedef float float4v __attribute__((ext_vector_type(4)));
typedef int int4v __attribute__((ext_vector_type(4)));
typedef unsigned int uint4v __attribute__((ext_vector_type(4)));

__device__ __forceinline__ float bf2f(unsigned short u) {
  union { unsigned int i; float f; } x; x.i = ((unsigned int)u) << 16; return x.f;
}

__device__ __forceinline__ void async_copy16(const void* g, void* l) {
  __builtin_amdgcn_global_load_lds((const __attribute__((address_space(1))) void*)g,
                                   (__attribute__((address_space(3))) void*)l, 16, 0, 0);
}

// ---------------- GEMM core (f16 A): C[M x ldc] = A[M x K] * BT[N x K]^T, fp32 accum ----------------
// 128x128 tile, BK=32, 256 threads (4 waves, each 64x64 via 4x4 mfma_f32_16x16x32_f16).
// T3+T4 counted-vmcnt triple-buffer pipeline. PROVEN BEST ASSEMBLY (r14 = 186.2us) — restored
// after r15's regression, honoring the pre-committed revert threshold.
// LEDGER r3/r6: LDS bank conflicts off the critical path at 64B rows (0-conflict endpoint = no gain).
// LEDGER r4/r5: not L2-BW-bound; 4 schedule variants all ~60+/-3us at the adj shape.
// LEDGER r7/r8: per-lane A-fragment global loads FAIL (64 lines/wave); A must stage coalesced.
// LEDGER r12: device-scope atomics to one cache line from 4096 blocks = ~180us ping-pong.
// LEDGER conversion placement (r9/r10/r15, FINAL): standalone BW pass (best) >> at-ds_write
//   (+35us, rides lgkm path) >> at-fragment-read (+47us: 72KB LDS drops 3->2 blocks/CU,
//   pack VALU pinned between lgkmcnt and MFMA, bank conflicts +50%). Keep the separate pass.
template <typename OutT>
__device__ __forceinline__ void gemm_core(
    const _Float16* __restrict__ A, const _Float16* __restrict__ BT,
    OutT* __restrict__ C, int K, int ldc, int klen, long csz,
    int lin, int nbx, int nby, int total,
    _Float16* __restrict__ sA, _Float16* __restrict__ sB)
{
  // ---- XCD-aware swizzle: same-XCD blocks get contiguous (kz, m, n-fastest) tiles ----
  int tile = ((total & 7) == 0) ? ((lin & 7) * (total >> 3) + (lin >> 3)) : lin;
  const int n_idx = tile % nbx;
  const int rem   = tile / nbx;
  const int m_idx = rem % nby;
  const int kz    = rem / nby;

  const int n0 = n_idx * 128;
  const int m0 = m_idx * 128;
  const int kbeg = kz * klen;
  OutT* Cz = C + (long)kz * csz;

  const int t = threadIdx.x;
  const int w = t >> 6;
  const int lane = t & 63;
  const int wm = (w >> 1) << 6;
  const int wn = (w & 1) << 6;

  floatx4 acc[4][4] = {};

  const int l4 = lane >> 2;         // 0..15 (row within 16-row chunk)
  const int kk = (lane & 3) << 3;   // k element offset 0,8,16,24
  const int c0 = w << 1;            // this wave stages chunks c0, c0+1

  const _Float16* gA = A + (long)m0 * K;
  const _Float16* gBT = BT + (long)n0 * K;

  const int koff = (lane >> 4) << 3;   // quad*8
  const int rA = wm + (lane & 15);
  const int rB = wn + (lane & 15);

  const int nt = klen >> 5;            // number of BK=32 K-steps

  auto STAGE = [&](int buf, int k0) {
#pragma unroll
    for (int p = 0; p < 2; ++p) {
      const int c = c0 + p;
      const int row = c * 16 + l4;
      async_copy16(gA + (long)row * K + k0 + kk, &sA[buf * 4096 + c * 512 + lane * 8]);
      async_copy16(gBT + (long)row * K + k0 + kk, &sB[buf * 4096 + c * 512 + lane * 8]);
    }
  };

  // prologue: stage tiles 0 and 1 (8 loads/thread in flight)
  STAGE(0, kbeg);
  if (nt > 1) STAGE(1, kbeg + 32);

  int cur = 0;
  for (int it = 0; it < nt; ++it) {
    const int k0 = kbeg + it * 32;

    // wait for tile `it` (4 loads) to land; tile it+1's 4 stay in flight
    if (it + 1 < nt) asm volatile("s_waitcnt vmcnt(4)" ::: "memory");
    else             asm volatile("s_waitcnt vmcnt(0)" ::: "memory");
    __builtin_amdgcn_s_barrier();     // all waves' tile-`it` loads visible

    half8 af[4], bf[4];
#pragma unroll
    for (int i = 0; i < 4; ++i)
      af[i] = *(const half8*)&sA[cur * 4096 + (rA + i * 16) * 32 + koff];
#pragma unroll
    for (int i = 0; i < 4; ++i)
      bf[i] = *(const half8*)&sB[cur * 4096 + (rB + i * 16) * 32 + koff];

    asm volatile("s_waitcnt lgkmcnt(0)" ::: "memory");
    __builtin_amdgcn_sched_barrier(0);   // rule #18: MFMA must not hoist past the wait

    // stage tile it+2 into the buffer freed above (held tile it-1; all reads done)
    const int nxt = (cur + 2 >= 3) ? cur - 1 : cur + 2;
    if (it + 2 < nt) STAGE(nxt, k0 + 64);

#pragma unroll
    for (int i = 0; i < 4; ++i)
#pragma unroll
      for (int j = 0; j < 4; ++j)
        acc[i][j] = __builtin_amdgcn_mfma_f32_16x16x32_f16(af[i], bf[j], acc[i][j], 0, 0, 0);

    cur = (cur + 1 >= 3) ? 0 : cur + 1;
  }

  const int q4 = (lane >> 4) << 2;
#pragma unroll
  for (int i = 0; i < 4; ++i) {
#pragma unroll
    for (int j = 0; j < 4; ++j) {
      const int gr = m0 + wm + i * 16 + q4;
      const int gc = n0 + wn + j * 16 + (lane & 15);
#pragma unroll
      for (int r = 0; r < 4; ++r)
        Cz[(long)(gr + r) * ldc + gc] = (OutT)acc[i][j][r];
    }
  }
}

template <typename OutT>
__global__ __launch_bounds__(256) void gemm_bt(
    const _Float16* __restrict__ A, const _Float16* __restrict__ BT,
    OutT* __restrict__ C, int K, int ldc, int klen, long csz)
{
  __shared__ _Float16 sA[3 * 128 * 32];
  __shared__ _Float16 sB[3 * 128 * 32];
  const int nbx = gridDim.x, nby = gridDim.y;
  const int total = nbx * nby * gridDim.z;
  const int lin = blockIdx.x + nbx * (blockIdx.y + nby * blockIdx.z);
  gemm_core<OutT>(A, BT, C, K, ldc, klen, csz, lin, nbx, nby, total, sA, sB);
}

// ---------------- prep: detect + cvt_h + cvt_a + transpose_w + adj cvt (ALL independent, 1 launch) ----------------
// LEDGER r10->r11: per-block local flag recompute (2KB L2-broadcast) kills the flag round-trip.
// LEDGER r13->r14: adj int32->f16 cvt HERE (pure-BW work batched), ht GEMM runs uncontended.
// Blocks 0..1023: cvt_h; 1024: cvt_a; 1025..1152: transpose_w (8x16); 1153..9344: adj cvt.
__global__ __launch_bounds__(256) void prep_kernel(
    const void* __restrict__ h, _Float16* __restrict__ hF,
    const void* __restrict__ a, float* __restrict__ aF,
    const void* __restrict__ W, _Float16* __restrict__ WT,
    const int* __restrict__ adj, _Float16* __restrict__ adjF)
{
  const int t = threadIdx.x;
  const int b = blockIdx.x;

  if (b >= 1153) {
    // ---- adj int32 (0/1) -> f16, 8 elems/thread ----
    const int i = (b - 1153) * 256 + t;
    int4v A = ((const int4v*)adj)[2 * i];
    int4v B = ((const int4v*)adj)[2 * i + 1];
    half8 o;
#pragma unroll
    for (int e = 0; e < 4; ++e) {
      o[e]     = (_Float16)(A[e] > 0 ? 1.0f : 0.0f);
      o[4 + e] = (_Float16)(B[e] > 0 ? 1.0f : 0.0f);
    }
    ((half8*)adjF)[i] = o;
    return;
  }

  __shared__ int red[256];
  __shared__ _Float16 tile[64][72];
  const unsigned short* hb = (const unsigned short*)h;
  int cnt = 0;
#pragma unroll
  for (int q = 0; q < 4; ++q) {
    int e = (hb[t * 4 + q] >> 7) & 0xFF;
    cnt += (e >= 115 && e <= 135) ? 1 : 0;
  }
  red[t] = cnt; __syncthreads();
  for (int s = 128; s > 0; s >>= 1) { if (t < s) red[t] += red[t + s]; __syncthreads(); }
  const int bf = (red[0] >= 900) ? 1 : 0;   // uniform across block after reduce
  __syncthreads();

  if (b < 1024) {
    // ---- cvt_h: h (bf16 or fp32) -> f16, 8 elems/thread ----
    const int i = b * 256 + t;
    half8 o;
    if (bf) {
      union { uint4v v; unsigned short s[8]; } u;
      u.v = ((const uint4v*)h)[i];
#pragma unroll
      for (int e = 0; e < 8; ++e) o[e] = (_Float16)bf2f(u.s[e]);
    } else {
      const float4v* f = (const float4v*)h + 2 * i;
      float4v x0 = f[0], x1 = f[1];
#pragma unroll
      for (int e = 0; e < 4; ++e) { o[e] = (_Float16)x0[e]; o[4 + e] = (_Float16)x1[e]; }
    }
    ((half8*)hF)[i] = o;
  } else if (b == 1024) {
    // ---- cvt_a: a (bf16 or fp32) -> fp32, 2048 elems ----
#pragma unroll
    for (int e = 0; e < 8; ++e) {
      int idx = t * 8 + e;
      aF[idx] = bf ? bf2f(((const unsigned short*)a)[idx]) : ((const float*)a)[idx];
    }
  } else {
    // ---- transpose_w: W[512 x 1024] -> WT[1024 x 512] f16 ----
    const int bb = b - 1025;
    const int k0 = (bb & 7) * 64, n0 = (bb >> 3) * 64;
    const int r = t >> 3, c = t & 7;
#pragma unroll
    for (int q = 0; q < 2; ++q) {
      int k = r + q * 32;
      half8 v;
      if (bf) {
        union { uint4v vv; unsigned short s[8]; } u;
        u.vv = *(const uint4v*)&((const unsigned short*)W)[(long)(k0 + k) * HD + n0 + c * 8];
#pragma unroll
        for (int e = 0; e < 8; ++e) v[e] = (_Float16)bf2f(u.s[e]);
      } else {
        const float4v* f = (const float4v*)&((const float*)W)[(long)(k0 + k) * HD + n0 + c * 8];
        float4v x0 = f[0], x1 = f[1];
#pragma unroll
        for (int e = 0; e < 4; ++e) { v[e] = (_Float16)x0[e]; v[4 + e] = (_Float16)x1[e]; }
      }
      *(half8*)&tile[k][c * 8] = v;
    }
    __syncthreads();
#pragma unroll
    for (int q = 0; q < 2; ++q) {
      int n = r + q * 32;
      half8 o;
#pragma unroll
      for (int e = 0; e < 8; ++e) o[e] = tile[c * 8 + e][n];
      *(half8*)&WT[(long)(n0 + n) * F_IN + k0 + c * 8] = o;
    }
  }
}

// ---------------- tgt[h,i] = sum_d leaky_relu(ht[i, h*256+d]) * aF[h, 256+d]  (no atomics) ----------------
__global__ void tgt_kernel(const _Float16* __restrict__ ht, const float* __restrict__ aF,
                           float* __restrict__ tgt) {
  const int i = blockIdx.x;
  const int t = threadIdx.x, h = t >> 6, lane = t & 63;
  half4 v = *(const half4*)&ht[(long)i * HD + h * NHID + lane * 4];
  float4v av = *(const float4v*)&aF[h * 512 + NHID + lane * 4];
  float s = 0.f;
#pragma unroll
  for (int e = 0; e < 4; ++e) {
    float x = (float)v[e];
    x = x > 0.f ? x : 0.1f * x;
    s += x * av[e];
  }
#pragma unroll
  for (int o = 32; o > 0; o >>= 1) s += __shfl_down(s, o);
  if (lane == 0) tgt[h * N_NODES + i] = s;
}

// ---------------- scaled transpose + in-block row-max + inline w=exp(tgt-m) ----------------
// LEDGER r12->r13: maxexp eliminated WITHOUT atomics: per-block local row-max recompute
// (L2-broadcast + wave/LDS reduce; max order-independent -> bit-identical m).
// grid (64,17): y<16 = transpose tiles; y==16 = VT w-rows 1024..1027.
__global__ void scaled_transpose_kernel(const _Float16* __restrict__ ht, const float* __restrict__ tgt,
                                        _Float16* __restrict__ VT) {
  __shared__ _Float16 tile[64][72];
  __shared__ float red[4];
  const int j0 = blockIdx.x * 64;
  const int t = threadIdx.x;
  const int w = t >> 6, lane = t & 63;

  if (blockIdx.y == 16) {
    // wave w: reduce head w's row (64 lanes x 64 elems), then write 64 w-values
    const float* row = tgt + w * N_NODES;
    float m = -3.0e38f;
#pragma unroll
    for (int q = 0; q < 16; ++q) {
      float4v v = *(const float4v*)&row[(lane + q * 64) * 4];
#pragma unroll
      for (int e = 0; e < 4; ++e) m = fmaxf(m, v[e]);
    }
#pragma unroll
    for (int o = 32; o > 0; o >>= 1) m = fmaxf(m, __shfl_down(m, o));
    if (lane == 0) red[w] = m;
    __syncthreads();
    const float mh = red[w];
    const int j = j0 + lane;
    VT[(long)(HD + w) * N_NODES + j] = (_Float16)__expf(row[j] - mh);
    return;
  }

  const int n0 = blockIdx.y * 64;
  const int h = n0 >> 8;
  const float* row = tgt + h * N_NODES;
  const int r = t >> 3, c = t & 7;
  // tile loads + row-max partials both land before the single barrier
#pragma unroll
  for (int q = 0; q < 2; ++q) {
    int j = r + q * 32;
    *(half8*)&tile[j][c * 8] = *(const half8*)&ht[(long)(j0 + j) * HD + n0 + c * 8];
  }
  float m = -3.0e38f;
#pragma unroll
  for (int q = 0; q < 4; ++q) {
    float4v v = *(const float4v*)&row[(t + q * 256) * 4];
#pragma unroll
    for (int e = 0; e < 4; ++e) m = fmaxf(m, v[e]);
  }
#pragma unroll
  for (int o = 32; o > 0; o >>= 1) m = fmaxf(m, __shfl_down(m, o));
  if (lane == 0) red[w] = m;
  __syncthreads();
  m = fmaxf(fmaxf(red[0], red[1]), fmaxf(red[2], red[3]));

  float w8[8];
#pragma unroll
  for (int e = 0; e < 8; ++e)
    w8[e] = __expf(row[j0 + c * 8 + e] - m);
#pragma unroll
  for (int q = 0; q < 2; ++q) {
    int n = r + q * 32;
    half8 o;
#pragma unroll
    for (int e = 0; e < 8; ++e) {
      int j = c * 8 + e;
      o[e] = (_Float16)(w8[e] * (float)tile[j][n]);
    }
    *(half8*)&VT[(long)(n0 + n) * N_NODES + j0 + c * 8] = o;
  }
}

// ---------------- out[i,d] = fp32( 0.25 * sum_h (sum_z Sz[i, h*256+d]) / (sum_z Sz[i, 1024+h]) ) ----------------
__global__ void epilogue_kernel(const float* __restrict__ S, float* __restrict__ out, int ns) {
  const int i = blockIdx.x, d = threadIdx.x;
  const long SZ = (long)N_NODES * NPAD;
  float num[4] = {0.f, 0.f, 0.f, 0.f};
  float den[4] = {0.f, 0.f, 0.f, 0.f};
  for (int z = 0; z < ns; ++z) {
    const float* row = S + z * SZ + (long)i * NPAD;
#pragma unroll
    for (int h = 0; h < 4; ++h) {
      num[h] += row[h * NHID + d];
      den[h] += row[HD + h];
    }
  }
  float r = 0.f;
#pragma unroll
  for (int h = 0; h < 4; ++h) r += num[h] / den[h];
  out[(long)i * NHID + d] = 0.25f * r;
}

extern "C" void kernel_launch(void* const* d_in, const int* in_sizes, int n_in,
                              void* d_out, int out_size, void* d_ws, size_t ws_size,
                              hipStream_t stream) {
  // map inputs by element count: h=2097152, adj=16777216, W=524288, a=2048
  const void* h = nullptr; const int* adj = nullptr; const void* W = nullptr; const void* a = nullptr;
  for (int i = 0; i < n_in; ++i) {
    switch (in_sizes[i]) {
      case 2097152:  h   = d_in[i]; break;
      case 16777216: adj = (const int*)d_in[i]; break;
      case 524288:   W   = d_in[i]; break;
      case 2048:     a   = d_in[i]; break;
      default: break;
    }
  }
  float* out = (float*)d_out;  // fp32 [4096,256]

  char* ws = (char*)d_ws;
  const size_t OFF_ADJF = 0;                       // 33,554,432  adj as f16
  const size_t OFF_VT   = 33554432;                //  9,437,184  VT [1152 x 4096] f16
  const size_t OFF_TGT  = OFF_VT + 9437184;        //     65,536  tgt fp32 [4 x 4096]
  const size_t OFF_WBUF = OFF_TGT + 65536;         //     65,536  (spare)
  const size_t OFF_M    = OFF_WBUF + 65536;        //        256  (spare)
  const size_t OFF_AF   = OFF_M + 256;             //      8,192  a as fp32
  const size_t OFF_X    = OFF_AF + 8192;           // overlap region
  const size_t SPART    = 18874368;                // one fp32 S partial [4096 x 1152]

  // split-K ns=2 (LEDGER r9: halves S write + epilogue re-read vs ns=4; 576 blocks saturate)
  int ns = 1;
  if      (ws_size >= OFF_X + 2 * SPART) ns = 2;
  if (ws_size < OFF_X + SPART || !h || !adj || !W || !a) return;

  _Float16* adjF = (_Float16*)(ws + OFF_ADJF);
  _Float16* VT   = (_Float16*)(ws + OFF_VT);
  float*    tgt  = (float*)(ws + OFF_TGT);
  float*    aF   = (float*)(ws + OFF_AF);
  // region X: hF/WT/ht live until scaled_transpose; S partials (adj-GEMM output) alias them after
  _Float16* hF = (_Float16*)(ws + OFF_X);                  // 4,194,304
  _Float16* WT = (_Float16*)(ws + OFF_X + 4194304);        // 1,048,576
  _Float16* ht = (_Float16*)(ws + OFF_X + 5242880);        // 8,388,608
  float*    S  = (float*)(ws + OFF_X);                     // ns x 18,874,368 (aliases dead hF/WT/ht)

  // prep: detect(local) + cvt_h + cvt_a + transpose_w + adj cvt in ONE launch (all pure-BW)
  prep_kernel<<<9345, 256, 0, stream>>>(h, hF, a, aF, W, WT, adj, adjF);
  // ht[4096 x 1024] = h @ W  (standalone: uncontended HBM/L2)
  gemm_bt<_Float16><<<dim3(8, 32, 1), 256, 0, stream>>>(hF, WT, ht, F_IN, HD, F_IN, 0);
  tgt_kernel<<<4096, 256, 0, stream>>>(ht, aF, tgt);
  scaled_transpose_kernel<<<dim3(64, 17), 256, 0, stream>>>(ht, tgt, VT);
  // S_z[4096 x 1152] = adj @ [w*ht | w] over K-slice z
  gemm_bt<float><<<dim3(9, 32, ns), 256, 0, stream>>>(adjF, VT, S, N_NODES, NPAD,
                                                      N_NODES / ns, (long)N_NODES * NPAD);
  epilogue_kernel<<<4096, 256, 0, stream>>>(S, out, ns);
}